// Round 6
// baseline (333.063 us; speedup 1.0000x reference)
//
#include <hip/hip_runtime.h>
#include <hip/hip_bf16.h>

#define BB   256
#define II   1152
#define DIN  8
#define OO   10
#define DOUT 16

// Pass kernel, batch-on-lanes: lane = dsub*32 + bl.
// Lane owns batch b = bg*32+bl and d-half dsub (8 d's in registers).
// w loads are uniform within each 32-lane half -> 2 cache segments per instr
// (the validated R5 port win). Registers: s[10][8] + xh[10][8] (~190 VGPR,
// launch_bounds(256,2) -> no spill, 2 waves/SIMD). V lives in LDS (padded
// rows, re-read per (i,o)) instead of 80 more registers -- DS pipe is idle.
// Accumulation over i uses atomicAdd into a single plane, decoupling the
// grid (512 blocks = 2/CU for occupancy) from workspace layout.
template<int K>
__global__ __launch_bounds__(256, 2) void pass_kernel(
    const float* __restrict__ x,     // fp32 [B][I][DIN]
    const float* __restrict__ w,     // fp32 [O][I][DOUT][DIN]
    const float* __restrict__ V,     // fp32 [B][O][DOUT]
    float* __restrict__ plane)       // fp32 [B][O][DOUT] accumulator (pre-zeroed)
{
  const int tid  = threadIdx.x;
  const int lane = tid & 63;
  const int wv   = tid >> 6;
  const int bl   = lane & 31;
  const int dsub = lane >> 5;          // which d-half this lane owns
  const int bg   = blockIdx.x & 7;     // batch group (32 b each)
  const int b    = bg * 32 + bl;
  // wave's i-range: column c in [0,256) per bg, 4 or 5 i's each (1152/256=4.5)
  const int col  = (blockIdx.x >> 3) * 4 + wv;
  const int ista = (col * 9) >> 1;
  const int iend = ((col + 1) * 9) >> 1;

  __shared__ float Vl[32][164];        // padded: 164%32=4, 656B rows (16B-aligned)
  __shared__ float red[4][32][81];     // 81: bank-conflict-free block reduce

  if (K >= 1) {
    // stage V[bg*32 .. +32][*] into LDS, coalesced
    const float* vsrc = V + (size_t)bg * 32 * OO * DOUT;
    for (int k = tid; k < 32 * 160 / 4; k += 256) {
      const float4 v4 = *(const float4*)(vsrc + k * 4);
      const int f = k * 4, row = f / 160, colf = f % 160;
      Vl[row][colf]     = v4.x;
      Vl[row][colf + 1] = v4.y;
      Vl[row][colf + 2] = v4.z;
      Vl[row][colf + 3] = v4.w;
    }
    __syncthreads();
  }

  float s[OO][8];
#pragma unroll
  for (int o = 0; o < OO; ++o)
#pragma unroll
    for (int dd = 0; dd < 8; ++dd) s[o][dd] = 0.f;

#pragma unroll 1
  for (int i = ista; i < iend; ++i) {
    const float* xp = x + ((size_t)b * II + i) * DIN;
    const float4 x0 = *(const float4*)(xp);
    const float4 x1 = *(const float4*)(xp + 4);

    float xh[OO][8];
    float t[OO];
#pragma unroll
    for (int o = 0; o < OO; ++o) {
      const float4* wp = (const float4*)(w + (((size_t)o * II + i) * DOUT + dsub * 8) * DIN);
#pragma unroll
      for (int dd = 0; dd < 8; ++dd) {
        const float4 wa = wp[2 * dd];
        const float4 wb = wp[2 * dd + 1];
        float a;
        a  = wa.x * x0.x + wa.y * x0.y + wa.z * x0.z + wa.w * x0.w;
        a += wb.x * x1.x + wb.y * x1.y + wb.z * x1.z + wb.w * x1.w;
        xh[o][dd] = a;
      }
      if (K >= 1) {
        const float4 va = *(const float4*)&Vl[bl][o * DOUT + dsub * 8];
        const float4 vb = *(const float4*)&Vl[bl][o * DOUT + dsub * 8 + 4];
        float tp;
        tp  = va.x * xh[o][0] + va.y * xh[o][1] + va.z * xh[o][2] + va.w * xh[o][3];
        tp += vb.x * xh[o][4] + vb.y * xh[o][5] + vb.z * xh[o][6] + vb.w * xh[o][7];
        t[o] = tp;
      }
    }

    if (K == 0) {
#pragma unroll
      for (int o = 0; o < OO; ++o)
#pragma unroll
        for (int dd = 0; dd < 8; ++dd) s[o][dd] += xh[o][dd];
    } else {
#pragma unroll
      for (int o = 0; o < OO; ++o)
        t[o] += __shfl_xor(t[o], 32, 64);    // combine the two d-halves
      float e[OO];
      float sum = 0.f;
#pragma unroll
      for (int o = 0; o < OO; ++o) { e[o] = __expf(t[o]); sum += e[o]; }
      const float inv = __builtin_amdgcn_rcpf(sum);  // |t|<1 -> no overflow; 1-ulp ok
#pragma unroll
      for (int o = 0; o < OO; ++o) {
        const float c = e[o] * inv;
#pragma unroll
        for (int dd = 0; dd < 8; ++dd) s[o][dd] += c * xh[o][dd];
      }
    }
  }

  if (K == 0) {
#pragma unroll
    for (int o = 0; o < OO; ++o)
#pragma unroll
      for (int dd = 0; dd < 8; ++dd) s[o][dd] *= 0.1f;   // uniform softmax weight
  }

  __syncthreads();   // Vl no longer needed; red[] reuse is safe

  // Block reduce over the 4 waves (adjacent i-cols, same bg), then one
  // atomicAdd per float into the global plane. Two phases (one per d-half).
#pragma unroll 1
  for (int half = 0; half < 2; ++half) {
    if (dsub == half) {
#pragma unroll
      for (int o = 0; o < OO; ++o)
#pragma unroll
        for (int dd = 0; dd < 8; ++dd)
          red[wv][bl][o * 8 + dd] = s[o][dd];
    }
    __syncthreads();
    for (int k = tid; k < 32 * 80; k += 256) {
      const int rb = k / 80, idx = k % 80;
      const float v = red[0][rb][idx] + red[1][rb][idx]
                    + red[2][rb][idx] + red[3][rb][idx];
      const int o = idx >> 3, dd = idx & 7;
      unsafeAtomicAdd(&plane[(((size_t)bg * 32 + rb) * OO + o) * DOUT + half * 8 + dd], v);
    }
    __syncthreads();
  }
}

// Squash the accumulated plane, update V / write final output.
template<int K>
__global__ __launch_bounds__(256) void reduce_kernel(
    const float* __restrict__ plane,   // [B*O*DOUT]
    float* __restrict__ V,             // [B*O*DOUT]
    float* __restrict__ out)           // fp32 [B*O*DOUT]
{
  const int idx = blockIdx.x * 256 + threadIdx.x;    // over B*O*DOUT = 40960
  const float s = plane[idx];

  // squash over the 16 Dout lanes (contiguous 16-lane groups share (b,o))
  float sq = s * s;
  sq += __shfl_xor(sq, 1);
  sq += __shfl_xor(sq, 2);
  sq += __shfl_xor(sq, 4);
  sq += __shfl_xor(sq, 8);
  const float mag = sqrtf(sq);
  const float v = sq / (1.f + sq) * (s / (mag + 1e-8f));

  if (K == 0)      V[idx] = v;
  else if (K == 1) V[idx] += v;
  else             out[idx] = v;
}

extern "C" void kernel_launch(void* const* d_in, const int* in_sizes, int n_in,
                              void* d_out, int out_size, void* d_ws, size_t ws_size,
                              hipStream_t stream) {
  const float* x = (const float*)d_in[0];   // fp32 [256,1152,8]
  const float* w = (const float*)d_in[1];   // fp32 [10,1152,16,8]
  float* out = (float*)d_out;               // fp32 [256,10,16]

  const size_t P = (size_t)BB * OO * DOUT;  // 40960 floats per plane
  float* s0 = (float*)d_ws;                 // 3 accumulator planes + V
  float* s1 = s0 + P;
  float* s2 = s1 + P;
  float* V  = s2 + P;

  hipMemsetAsync(s0, 0, 3 * P * sizeof(float), stream);  // zero the 3 planes

  const int pg = 512;                       // 2 blocks/CU, 8 waves/CU
  const int rg = (int)(P / 256);            // 160 blocks

  pass_kernel<0><<<pg, 256, 0, stream>>>(x, w, V, s0);
  reduce_kernel<0><<<rg, 256, 0, stream>>>(s0, V, out);
  pass_kernel<1><<<pg, 256, 0, stream>>>(x, w, V, s1);
  reduce_kernel<1><<<rg, 256, 0, stream>>>(s1, V, out);
  pass_kernel<2><<<pg, 256, 0, stream>>>(x, w, V, s2);
  reduce_kernel<2><<<rg, 256, 0, stream>>>(s2, V, out);
}

// Round 7
// 270.847 us; speedup vs baseline: 1.2297x; 1.2297x over previous
//
#include <hip/hip_runtime.h>
#include <hip/hip_bf16.h>

#define BB   256
#define II   1152
#define DIN  8
#define OO   10
#define DOUT 16
#define NIB  32

// Pass kernel, quarter-d batch-on-lanes: lane = dsub*16 + bl.
// Lane owns batch b = bg*16+bl and d-quarter dsub (4 d's in registers).
// w loads are uniform within each 16-lane group -> ~4 segments/instr, and
// amortized over 16 batches (the validated R5/R6 port win) while keeping
// accumulator pressure at s[10][4]+xh[10][4] = 80 regs (~140 peak, fits
// launch_bounds(256,3) cap of 170 -- the R5/R6 spill killer avoided).
// Routing dot t[o]: 4 in-register FMAs vs LDS-resident V + shfl_xor(16,32).
// Block = 4 waves stacked on i (9 i each), LDS block-reduce -> s_partial[NIB].
template<int K>
__global__ __launch_bounds__(256, 3) void pass_kernel(
    const float* __restrict__ x,   // fp32 [B][I][DIN]
    const float* __restrict__ w,   // fp32 [O][I][DOUT][DIN]
    const float* __restrict__ V,   // fp32 [B][O][DOUT]
    float* __restrict__ sp)        // fp32 [NIB][B][O][DOUT]
{
  const int tid  = threadIdx.x;
  const int lane = tid & 63;
  const int wv   = tid >> 6;
  const int bl   = lane & 15;
  const int dsub = lane >> 4;          // 0..3: d-quarter
  const int bg   = blockIdx.x & 15;    // batch group (16 b each)
  const int ibM  = blockIdx.x >> 4;    // 0..31: i-plane
  const int b    = bg * 16 + bl;
  const int i0   = (ibM * 4 + wv) * 9;

  __shared__ float Vl[16][164];        // V slice, padded rows (656 B, 16B-aligned)
  __shared__ float red[4][16][168];    // block-reduce buffer

  if (K >= 1) {
    const float* vsrc = V + (size_t)bg * 16 * OO * DOUT;
    for (int k = tid; k < 16 * 160; k += 256)
      Vl[k / 160][k % 160] = vsrc[k];
    __syncthreads();
  }

  float s[OO][4];
#pragma unroll
  for (int o = 0; o < OO; ++o)
#pragma unroll
    for (int dd = 0; dd < 4; ++dd) s[o][dd] = 0.f;

#pragma unroll 1
  for (int ii = 0; ii < 9; ++ii) {
    const int i = i0 + ii;
    const float* xp = x + ((size_t)b * II + i) * DIN;
    const float4 x0 = *(const float4*)(xp);
    const float4 x1 = *(const float4*)(xp + 4);

    float xh[OO][4];
    float t[OO];
#pragma unroll
    for (int o = 0; o < OO; ++o) {
      const float4* wp = (const float4*)(w + (((size_t)o * II + i) * DOUT + dsub * 4) * DIN);
#pragma unroll
      for (int dd = 0; dd < 4; ++dd) {
        const float4 wa = wp[2 * dd];
        const float4 wb = wp[2 * dd + 1];
        xh[o][dd] = wa.x * x0.x + wa.y * x0.y + wa.z * x0.z + wa.w * x0.w
                  + wb.x * x1.x + wb.y * x1.y + wb.z * x1.z + wb.w * x1.w;
      }
      if (K >= 1) {
        const float4 vv = *(const float4*)&Vl[bl][o * DOUT + dsub * 4];
        t[o] = vv.x * xh[o][0] + vv.y * xh[o][1]
             + vv.z * xh[o][2] + vv.w * xh[o][3];
      }
    }

    if (K == 0) {
#pragma unroll
      for (int o = 0; o < OO; ++o)
#pragma unroll
        for (int dd = 0; dd < 4; ++dd) s[o][dd] += xh[o][dd];
    } else {
#pragma unroll
      for (int o = 0; o < OO; ++o) {
        t[o] += __shfl_xor(t[o], 16, 64);    // combine d-quarter pairs
        t[o] += __shfl_xor(t[o], 32, 64);    // all four quarters
      }
      float e[OO];
      float sum = 0.f;
#pragma unroll
      for (int o = 0; o < OO; ++o) { e[o] = __expf(t[o]); sum += e[o]; }
      const float inv = __builtin_amdgcn_rcpf(sum);  // |t|<1 -> no overflow; 1-ulp ok
#pragma unroll
      for (int o = 0; o < OO; ++o) {
        const float c = e[o] * inv;
#pragma unroll
        for (int dd = 0; dd < 4; ++dd) s[o][dd] += c * xh[o][dd];
      }
    }
  }

  if (K == 0) {
#pragma unroll
    for (int o = 0; o < OO; ++o)
#pragma unroll
      for (int dd = 0; dd < 4; ++dd) s[o][dd] *= 0.1f;   // uniform softmax weight
  }

  // Deterministic block reduce over the 4 i-stacked waves, then plain stores
  // into this block's own (ibM, bg) slice -- no atomics.
#pragma unroll
  for (int o = 0; o < OO; ++o)
    *(float4*)&red[wv][bl][o * DOUT + dsub * 4] =
        make_float4(s[o][0], s[o][1], s[o][2], s[o][3]);
  __syncthreads();
  for (int k = tid; k < 16 * 160; k += 256) {
    const int rb = k / 160, idx = k % 160;
    const float v = red[0][rb][idx] + red[1][rb][idx]
                  + red[2][rb][idx] + red[3][rb][idx];
    sp[((size_t)ibM * BB + bg * 16 + rb) * (OO * DOUT) + idx] = v;
  }
}

// Combine partials over NIB i-planes, squash, update V / write final output.
template<int K>
__global__ __launch_bounds__(256) void reduce_kernel(
    const float* __restrict__ s_partial,   // [NIB][B*O*DOUT]
    float* __restrict__ V,                 // [B*O*DOUT]
    float* __restrict__ out)               // fp32 [B*O*DOUT]
{
  const int idx = blockIdx.x * 256 + threadIdx.x;    // over B*O*DOUT = 40960
  float s = 0.f;
#pragma unroll
  for (int ib = 0; ib < NIB; ++ib)
    s += s_partial[(size_t)ib * (BB * OO * DOUT) + idx];

  // squash over the 16 Dout lanes (contiguous 16-lane groups share (b,o))
  float sq = s * s;
  sq += __shfl_xor(sq, 1);
  sq += __shfl_xor(sq, 2);
  sq += __shfl_xor(sq, 4);
  sq += __shfl_xor(sq, 8);
  const float mag = sqrtf(sq);
  const float v = sq / (1.f + sq) * (s / (mag + 1e-8f));

  if (K == 0)      V[idx] = v;
  else if (K == 1) V[idx] += v;
  else             out[idx] = v;
}

extern "C" void kernel_launch(void* const* d_in, const int* in_sizes, int n_in,
                              void* d_out, int out_size, void* d_ws, size_t ws_size,
                              hipStream_t stream) {
  const float* x = (const float*)d_in[0];   // fp32 [256,1152,8]
  const float* w = (const float*)d_in[1];   // fp32 [10,1152,16,8]
  float* out = (float*)d_out;               // fp32 [256,10,16]

  float* s_partial = (float*)d_ws;                             // NIB*B*O*DOUT floats (5.2 MB)
  float* V = s_partial + (size_t)NIB * BB * OO * DOUT;         // B*O*DOUT floats

  const int pg = 512;                       // 16 bg x 32 i-planes; 2 blocks/CU
  const int rg = (BB * OO * DOUT) / 256;    // 160 blocks

  pass_kernel<0><<<pg, 256, 0, stream>>>(x, w, V, s_partial);
  reduce_kernel<0><<<rg, 256, 0, stream>>>(s_partial, V, out);
  pass_kernel<1><<<pg, 256, 0, stream>>>(x, w, V, s_partial);
  reduce_kernel<1><<<rg, 256, 0, stream>>>(s_partial, V, out);
  pass_kernel<2><<<pg, 256, 0, stream>>>(x, w, V, s_partial);
  reduce_kernel<2><<<rg, 256, 0, stream>>>(s_partial, V, out);
}

// Round 8
// 204.277 us; speedup vs baseline: 1.6305x; 1.3259x over previous
//
#include <hip/hip_runtime.h>
#include <hip/hip_bf16.h>

#define BB   256
#define II   1152
#define DIN  8
#define OO   10
#define DOUT 16
#define NIB  32        // i-chunks / s_partial planes
#define CI   36        // i per block (II/NIB)
#define PCH  20        // padded LDS chunk stride per (o,dsub): dsub*20 mod 32 hits all 8 bank-quads

// Pass kernel: w staged global->LDS (coalesced), then conflict-free broadcast
// reads. Lane = bl*8 + dsub owns batch b and d-pair (2 d's) -> register budget
// ~130 by construction (s[10][2]+xh[10][2]+Vr[10][2]+t[10]), no allocator games.
// Block: 4 waves = 2 b-halves x 2 i-halves (18 i each, barrier counts align),
// double-buffered w tiles, LDS cross-half reduce, -> s_partial[NIB] planes.
template<int K>
__global__ __launch_bounds__(256, 3) void pass_kernel(
    const float* __restrict__ x,   // fp32 [B][I][DIN]
    const float* __restrict__ w,   // fp32 [O][I][DOUT][DIN]
    const float* __restrict__ V,   // fp32 [B][O][DOUT]
    float* __restrict__ sp)        // fp32 [NIB][B][O][DOUT]
{
  const int tid  = threadIdx.x;
  const int lane = tid & 63;
  const int wv   = tid >> 6;
  const int bh   = wv & 1;             // b-half of the block's 16 batches
  const int ih   = wv >> 1;            // i-half (18 i each)
  const int dsub = lane & 7;           // d-pair index (d = 2*dsub + dlo)
  const int bl   = lane >> 3;          // batch-in-wave (8)
  const int bg   = blockIdx.x & 15;    // 16 batches per block
  const int ic   = blockIdx.x >> 4;    // 0..31 i-chunk
  const int b    = bg * 16 + bh * 8 + bl;
  const int i0   = ic * CI + ih * 18;

  __shared__ float wt[2][2][OO * 8 * PCH];   // [ih][buf][1600] = 51.2 KB
  __shared__ float red[16][168];             // cross-ih reduce, padded rows

  float Vr[OO][2];
  if (K >= 1) {
#pragma unroll
    for (int o = 0; o < OO; ++o) {
      const float2 v2 = *(const float2*)(V + (b * OO + o) * DOUT + dsub * 2);
      Vr[o][0] = v2.x; Vr[o][1] = v2.y;
    }
  }

  float s[OO][2];
#pragma unroll
  for (int o = 0; o < OO; ++o) { s[o][0] = 0.f; s[o][1] = 0.f; }

  // staging: the 128 lanes of this i-half pair load w row i (1280 floats):
  // per o one coalesced 512 B load, scatter into padded LDS chunks.
  const int l128  = bh * 64 + lane;          // 0..127
  const int sdsub = l128 >> 4, sk = l128 & 15;
  const float* wbase = w + l128;

  #define STAGE(i, buf)                                                        \
    {                                                                          \
      float* dst = &wt[ih][buf][sdsub * PCH + sk];                             \
      _Pragma("unroll")                                                        \
      for (int o = 0; o < OO; ++o)                                             \
        dst[o * 8 * PCH] = wbase[(size_t)o * (II * DOUT * DIN) + (size_t)(i) * (DOUT * DIN)]; \
    }

  STAGE(i0, 0)
#pragma unroll 1
  for (int ii = 0; ii < 18; ++ii) {
    __syncthreads();                    // wt[ih][ii&1] ready; prev reads done
    const int cur = ii & 1;
    if (ii < 17) STAGE(i0 + ii + 1, cur ^ 1)

    const int i = i0 + ii;
    const float* xp = x + ((size_t)b * II + i) * DIN;
    const float4 x0 = *(const float4*)(xp);
    const float4 x1 = *(const float4*)(xp + 4);

    float xh[OO][2];
    float t[OO];
    const float* wtb = wt[ih][cur];
#pragma unroll 2
    for (int o = 0; o < OO; ++o) {
      const float4* wp = (const float4*)(wtb + (o * 8 + dsub) * PCH);
      const float4 wa = wp[0], wb2 = wp[1], wc = wp[2], wd = wp[3];
      xh[o][0] = wa.x * x0.x + wa.y * x0.y + wa.z * x0.z + wa.w * x0.w
               + wb2.x * x1.x + wb2.y * x1.y + wb2.z * x1.z + wb2.w * x1.w;
      xh[o][1] = wc.x * x0.x + wc.y * x0.y + wc.z * x0.z + wc.w * x0.w
               + wd.x * x1.x + wd.y * x1.y + wd.z * x1.z + wd.w * x1.w;
      if (K >= 1)
        t[o] = Vr[o][0] * xh[o][0] + Vr[o][1] * xh[o][1];
    }

    if (K == 0) {
#pragma unroll
      for (int o = 0; o < OO; ++o) { s[o][0] += xh[o][0]; s[o][1] += xh[o][1]; }
    } else {
#pragma unroll
      for (int o = 0; o < OO; ++o) {     // reduce over the 8 dsub lanes
        t[o] += __shfl_xor(t[o], 1);
        t[o] += __shfl_xor(t[o], 2);
        t[o] += __shfl_xor(t[o], 4);
      }
      float sum = 0.f;
#pragma unroll
      for (int o = 0; o < OO; ++o) { t[o] = __expf(t[o]); sum += t[o]; }
      const float inv = __builtin_amdgcn_rcpf(sum);  // |t|<1 pre-exp; 1-ulp ok
#pragma unroll
      for (int o = 0; o < OO; ++o) {
        const float c = t[o] * inv;
        s[o][0] += c * xh[o][0];
        s[o][1] += c * xh[o][1];
      }
    }
  }

  if (K == 0) {
#pragma unroll
    for (int o = 0; o < OO; ++o) { s[o][0] *= 0.1f; s[o][1] *= 0.1f; }
  }

  // cross-i-half reduce: ih=1 parks s in LDS; ih=0 adds and stores.
  if (ih == 1) {
#pragma unroll
    for (int o = 0; o < OO; ++o) {
      red[bh * 8 + bl][o * 16 + dsub * 2]     = s[o][0];
      red[bh * 8 + bl][o * 16 + dsub * 2 + 1] = s[o][1];
    }
  }
  __syncthreads();
  if (ih == 0) {
    float* out = sp + ((size_t)ic * BB + b) * (OO * DOUT);
    const float* rr = red[bh * 8 + bl];
#pragma unroll
    for (int o = 0; o < OO; ++o) {
      out[o * 16 + dsub * 2]     = s[o][0] + rr[o * 16 + dsub * 2];
      out[o * 16 + dsub * 2 + 1] = s[o][1] + rr[o * 16 + dsub * 2 + 1];
    }
  }
}

// Combine partials over NIB i-planes, squash, update V / write final output.
template<int K>
__global__ __launch_bounds__(256) void reduce_kernel(
    const float* __restrict__ s_partial,   // [NIB][B*O*DOUT]
    float* __restrict__ V,                 // [B*O*DOUT]
    float* __restrict__ out)               // fp32 [B*O*DOUT]
{
  const int idx = blockIdx.x * 256 + threadIdx.x;    // over B*O*DOUT = 40960
  float s = 0.f;
#pragma unroll
  for (int ib = 0; ib < NIB; ++ib)
    s += s_partial[(size_t)ib * (BB * OO * DOUT) + idx];

  // squash over the 16 Dout lanes (contiguous 16-lane groups share (b,o))
  float sq = s * s;
  sq += __shfl_xor(sq, 1);
  sq += __shfl_xor(sq, 2);
  sq += __shfl_xor(sq, 4);
  sq += __shfl_xor(sq, 8);
  const float mag = sqrtf(sq);
  const float v = sq / (1.f + sq) * (s / (mag + 1e-8f));

  if (K == 0)      V[idx] = v;
  else if (K == 1) V[idx] += v;
  else             out[idx] = v;
}

extern "C" void kernel_launch(void* const* d_in, const int* in_sizes, int n_in,
                              void* d_out, int out_size, void* d_ws, size_t ws_size,
                              hipStream_t stream) {
  const float* x = (const float*)d_in[0];   // fp32 [256,1152,8]
  const float* w = (const float*)d_in[1];   // fp32 [10,1152,16,8]
  float* out = (float*)d_out;               // fp32 [256,10,16]

  float* s_partial = (float*)d_ws;                             // NIB*B*O*DOUT floats (5.2 MB)
  float* V = s_partial + (size_t)NIB * BB * OO * DOUT;         // B*O*DOUT floats

  const int pg = 512;                       // 16 bg x 32 ic; 2 blocks/CU
  const int rg = (BB * OO * DOUT) / 256;    // 160 blocks

  pass_kernel<0><<<pg, 256, 0, stream>>>(x, w, V, s_partial);
  reduce_kernel<0><<<rg, 256, 0, stream>>>(s_partial, V, out);
  pass_kernel<1><<<pg, 256, 0, stream>>>(x, w, V, s_partial);
  reduce_kernel<1><<<rg, 256, 0, stream>>>(s_partial, V, out);
  pass_kernel<2><<<pg, 256, 0, stream>>>(x, w, V, s_partial);
  reduce_kernel<2><<<rg, 256, 0, stream>>>(s_partial, V, out);
}

// Round 9
// 197.663 us; speedup vs baseline: 1.6850x; 1.0335x over previous
//
#include <hip/hip_runtime.h>
#include <hip/hip_bf16.h>

#define BB   256
#define II   1152
#define DIN  8
#define OO   10
#define DOUT 16
#define NIB  32        // i-chunks / s_partial planes
#define CI   36        // i per block (II/NIB)
#define PCH  20        // LDS chunk stride per (o,dsub): dsub*20 mod 32 hits 8 distinct bank-quads (read conflict-free)

// Pass kernel: w staged global->LDS (coalesced float2), conflict-free broadcast
// reads. Lane = bl*8 + dsub owns batch b and d-pair. Block id swizzled so
// XCD = id%8 = ic%8: each XCD owns 4 ic-chunks (w slice 736 KB L2-resident,
// fetched from HBM once) -- kills the R8 3x w over-fetch that paced the kernel.
template<int K>
__global__ __launch_bounds__(256, 3) void pass_kernel(
    const float* __restrict__ x,   // fp32 [B][I][DIN]
    const float* __restrict__ w,   // fp32 [O][I][DOUT][DIN]
    const float* __restrict__ V,   // fp32 [B][O][DOUT]
    float* __restrict__ sp)        // fp32 [NIB][B][O][DOUT]
{
  const int tid  = threadIdx.x;
  const int lane = tid & 63;
  const int wv   = tid >> 6;
  const int bh   = wv & 1;             // b-half of the block's 16 batches
  const int ih   = wv >> 1;            // i-half (18 i each)
  const int dsub = lane & 7;           // d-pair index (d = 2*dsub + dlo)
  const int bl   = lane >> 3;          // batch-in-wave (8)
  const int ic   = blockIdx.x & 31;    // i-chunk -- fast-varying => XCD-local w
  const int bg   = blockIdx.x >> 5;    // 16 batches per block
  const int b    = bg * 16 + bh * 8 + bl;
  const int i0   = ic * CI + ih * 18;

  __shared__ float wt[2][2][OO * 8 * PCH];   // [ih][buf][1600] = 51.2 KB
  __shared__ float red[16][168];             // cross-ih reduce, padded rows

  float Vr[OO][2];
  if (K >= 1) {
#pragma unroll
    for (int o = 0; o < OO; ++o) {
      const float2 v2 = *(const float2*)(V + (b * OO + o) * DOUT + dsub * 2);
      Vr[o][0] = v2.x; Vr[o][1] = v2.y;
    }
  }

  float s[OO][2];
#pragma unroll
  for (int o = 0; o < OO; ++o) { s[o][0] = 0.f; s[o][1] = 0.f; }

  // staging: 128 lanes (this i-half's wave pair) load w row i (1280 floats)
  // as float2: per 2-o group one coalesced 512 B load per wave.
  const int p    = bh * 64 + lane;       // 0..127
  const int so   = p >> 6;               // o offset within 2-o group (== bh)
  const int idx2 = (p & 63) * 2;         // even element within o-row
  const int sds  = idx2 >> 4;            // dsub 0..7
  const int ssk  = idx2 & 15;            // 0,2,..,14

  #define STAGE(i, buf)                                                        \
    {                                                                          \
      _Pragma("unroll")                                                        \
      for (int og = 0; og < 5; ++og) {                                         \
        const int o = og * 2 + so;                                             \
        const float2 v2 = *(const float2*)(w + ((size_t)o * II + (i)) * (DOUT * DIN) + idx2); \
        *(float2*)&wt[ih][buf][(o * 8 + sds) * PCH + ssk] = v2;                \
      }                                                                        \
    }

  STAGE(i0, 0)
#pragma unroll 1
  for (int ii = 0; ii < 18; ++ii) {
    __syncthreads();                    // wt[ih][ii&1] ready; prev reads done
    const int cur = ii & 1;
    if (ii < 17) STAGE(i0 + ii + 1, cur ^ 1)

    const int i = i0 + ii;
    const float* xp = x + ((size_t)b * II + i) * DIN;
    const float4 x0 = *(const float4*)(xp);
    const float4 x1 = *(const float4*)(xp + 4);

    float xh[OO][2];
    float t[OO];
    const float* wtb = wt[ih][cur];
#pragma unroll 2
    for (int o = 0; o < OO; ++o) {
      const float4* wp = (const float4*)(wtb + (o * 8 + dsub) * PCH);
      const float4 wa = wp[0], wb2 = wp[1], wc = wp[2], wd = wp[3];
      xh[o][0] = wa.x * x0.x + wa.y * x0.y + wa.z * x0.z + wa.w * x0.w
               + wb2.x * x1.x + wb2.y * x1.y + wb2.z * x1.z + wb2.w * x1.w;
      xh[o][1] = wc.x * x0.x + wc.y * x0.y + wc.z * x0.z + wc.w * x0.w
               + wd.x * x1.x + wd.y * x1.y + wd.z * x1.z + wd.w * x1.w;
      if (K >= 1)
        t[o] = Vr[o][0] * xh[o][0] + Vr[o][1] * xh[o][1];
    }

    if (K == 0) {
#pragma unroll
      for (int o = 0; o < OO; ++o) { s[o][0] += xh[o][0]; s[o][1] += xh[o][1]; }
    } else {
#pragma unroll
      for (int o = 0; o < OO; ++o) {     // reduce over the 8 dsub lanes
        t[o] += __shfl_xor(t[o], 1);
        t[o] += __shfl_xor(t[o], 2);
        t[o] += __shfl_xor(t[o], 4);
      }
      float sum = 0.f;
#pragma unroll
      for (int o = 0; o < OO; ++o) { t[o] = __expf(t[o]); sum += t[o]; }
      const float inv = __builtin_amdgcn_rcpf(sum);  // |t|<1 pre-exp; 1-ulp ok
#pragma unroll
      for (int o = 0; o < OO; ++o) {
        const float c = t[o] * inv;
        s[o][0] += c * xh[o][0];
        s[o][1] += c * xh[o][1];
      }
    }
  }

  if (K == 0) {
#pragma unroll
    for (int o = 0; o < OO; ++o) { s[o][0] *= 0.1f; s[o][1] *= 0.1f; }
  }

  // cross-i-half reduce: ih=1 parks s in LDS; ih=0 adds and stores.
  if (ih == 1) {
#pragma unroll
    for (int o = 0; o < OO; ++o) {
      red[bh * 8 + bl][o * 16 + dsub * 2]     = s[o][0];
      red[bh * 8 + bl][o * 16 + dsub * 2 + 1] = s[o][1];
    }
  }
  __syncthreads();
  if (ih == 0) {
    float* out = sp + ((size_t)ic * BB + b) * (OO * DOUT);
    const float* rr = red[bh * 8 + bl];
#pragma unroll
    for (int o = 0; o < OO; ++o) {
      out[o * 16 + dsub * 2]     = s[o][0] + rr[o * 16 + dsub * 2];
      out[o * 16 + dsub * 2 + 1] = s[o][1] + rr[o * 16 + dsub * 2 + 1];
    }
  }
}

// Combine partials over NIB i-planes, squash, update V / write final output.
template<int K>
__global__ __launch_bounds__(256) void reduce_kernel(
    const float* __restrict__ s_partial,   // [NIB][B*O*DOUT]
    float* __restrict__ V,                 // [B*O*DOUT]
    float* __restrict__ out)               // fp32 [B*O*DOUT]
{
  const int idx = blockIdx.x * 256 + threadIdx.x;    // over B*O*DOUT = 40960
  float s = 0.f;
#pragma unroll
  for (int ib = 0; ib < NIB; ++ib)
    s += s_partial[(size_t)ib * (BB * OO * DOUT) + idx];

  // squash over the 16 Dout lanes (contiguous 16-lane groups share (b,o))
  float sq = s * s;
  sq += __shfl_xor(sq, 1);
  sq += __shfl_xor(sq, 2);
  sq += __shfl_xor(sq, 4);
  sq += __shfl_xor(sq, 8);
  const float mag = sqrtf(sq);
  const float v = sq / (1.f + sq) * (s / (mag + 1e-8f));

  if (K == 0)      V[idx] = v;
  else if (K == 1) V[idx] += v;
  else             out[idx] = v;
}

extern "C" void kernel_launch(void* const* d_in, const int* in_sizes, int n_in,
                              void* d_out, int out_size, void* d_ws, size_t ws_size,
                              hipStream_t stream) {
  const float* x = (const float*)d_in[0];   // fp32 [256,1152,8]
  const float* w = (const float*)d_in[1];   // fp32 [10,1152,16,8]
  float* out = (float*)d_out;               // fp32 [256,10,16]

  float* s_partial = (float*)d_ws;                             // NIB*B*O*DOUT floats (5.2 MB)
  float* V = s_partial + (size_t)NIB * BB * OO * DOUT;         // B*O*DOUT floats

  const int pg = 512;                       // 32 ic (fast) x 16 bg; 2 blocks/CU
  const int rg = (BB * OO * DOUT) / 256;    // 160 blocks

  pass_kernel<0><<<pg, 256, 0, stream>>>(x, w, V, s_partial);
  reduce_kernel<0><<<rg, 256, 0, stream>>>(s_partial, V, out);
  pass_kernel<1><<<pg, 256, 0, stream>>>(x, w, V, s_partial);
  reduce_kernel<1><<<rg, 256, 0, stream>>>(s_partial, V, out);
  pass_kernel<2><<<pg, 256, 0, stream>>>(x, w, V, s_partial);
  reduce_kernel<2><<<rg, 256, 0, stream>>>(s_partial, V, out);
}